// Round 3
// baseline (338.659 us; speedup 1.0000x reference)
//
#include <hip/hip_runtime.h>
#include <hip/hip_bf16.h>
#include <math.h>

#define NT 1200
#define NB 16384
#define NY 8
#define NGROUPS (NT * NB)            // 19,660,800 groups of 8 contiguous floats
#define NPAIRS  (NGROUPS / 2)        // 9,830,400 — pairs never straddle a t boundary
#define W_LOW  0.2f
#define W_HIGH 1.75f

typedef float f32x4 __attribute__((ext_vector_type(4)));   // clang vector: OK for nontemporal builtin

// Stage 1: grid-stride over PAIRS of 8-element groups (128 B/array/iter);
// accumulate w^2*(o-t)^2 per channel.
__global__ __launch_bounds__(256) void rmse_partial_kernel(
    const float* __restrict__ outp, const float* __restrict__ tgtp,
    float* __restrict__ ws)
{
    float acc[NY];
#pragma unroll
    for (int c = 0; c < NY; ++c) acc[c] = 0.0f;

    const int stride = gridDim.x * blockDim.x;
    const f32x4* __restrict__ o4 = reinterpret_cast<const f32x4*>(outp);
    const f32x4* __restrict__ t4 = reinterpret_cast<const f32x4*>(tgtp);

    for (int p = blockIdx.x * blockDim.x + threadIdx.x; p < NPAIRS; p += stride) {
        const int g   = p << 1;           // first group of the pair
        const int t   = g >> 14;          // g / NB ; same for both groups in pair
        const int mon = t % 12;
        const float w  = (mon >= 6 && mon <= 9) ? W_HIGH : W_LOW;
        const float w2 = w * w;

        const int base = g << 1;          // f32x4 index (2 per group)
        f32x4 a0 = __builtin_nontemporal_load(&o4[base]);
        f32x4 a1 = __builtin_nontemporal_load(&o4[base + 1]);
        f32x4 a2 = __builtin_nontemporal_load(&o4[base + 2]);
        f32x4 a3 = __builtin_nontemporal_load(&o4[base + 3]);
        f32x4 b0 = __builtin_nontemporal_load(&t4[base]);
        f32x4 b1 = __builtin_nontemporal_load(&t4[base + 1]);
        f32x4 b2 = __builtin_nontemporal_load(&t4[base + 2]);
        f32x4 b3 = __builtin_nontemporal_load(&t4[base + 3]);

        f32x4 d0 = a0 - b0;
        f32x4 d1 = a1 - b1;
        f32x4 d2 = a2 - b2;
        f32x4 d3 = a3 - b3;

        acc[0] += w2 * d0.x * d0.x;
        acc[1] += w2 * d0.y * d0.y;
        acc[2] += w2 * d0.z * d0.z;
        acc[3] += w2 * d0.w * d0.w;
        acc[4] += w2 * d1.x * d1.x;
        acc[5] += w2 * d1.y * d1.y;
        acc[6] += w2 * d1.z * d1.z;
        acc[7] += w2 * d1.w * d1.w;
        acc[0] += w2 * d2.x * d2.x;
        acc[1] += w2 * d2.y * d2.y;
        acc[2] += w2 * d2.z * d2.z;
        acc[3] += w2 * d2.w * d2.w;
        acc[4] += w2 * d3.x * d3.x;
        acc[5] += w2 * d3.y * d3.y;
        acc[6] += w2 * d3.z * d3.z;
        acc[7] += w2 * d3.w * d3.w;
    }

    // Wave (64-lane) reduction per channel.
#pragma unroll
    for (int c = 0; c < NY; ++c) {
        float v = acc[c];
#pragma unroll
        for (int off = 32; off > 0; off >>= 1)
            v += __shfl_down(v, off, 64);
        acc[c] = v;
    }

    __shared__ float sh[4][NY];           // 256 threads = 4 waves
    const int wave = threadIdx.x >> 6;
    const int lane = threadIdx.x & 63;
    if (lane == 0) {
#pragma unroll
        for (int c = 0; c < NY; ++c) sh[wave][c] = acc[c];
    }
    __syncthreads();

    if (threadIdx.x < NY) {
        const int c = threadIdx.x;
        float s = sh[0][c] + sh[1][c] + sh[2][c] + sh[3][c];
        atomicAdd(&ws[c], s);             // device-scope by default on CDNA
    }
}

// Stage 2: finalize — sum over channels of sqrt(mean).
__global__ void rmse_final_kernel(const float* __restrict__ ws, float* __restrict__ out)
{
    if (threadIdx.x == 0 && blockIdx.x == 0) {
        const float inv_n = 1.0f / (float)NGROUPS;   // mean over NT*NB per channel
        float s = 0.0f;
#pragma unroll
        for (int c = 0; c < NY; ++c)
            s += sqrtf(ws[c] * inv_n);
        out[0] = s;
    }
}

extern "C" void kernel_launch(void* const* d_in, const int* in_sizes, int n_in,
                              void* d_out, int out_size, void* d_ws, size_t ws_size,
                              hipStream_t stream) {
    const float* outp = (const float*)d_in[0];
    const float* tgtp = (const float*)d_in[1];
    float* ws  = (float*)d_ws;
    float* out = (float*)d_out;

    // Harness poisons d_ws once and never re-poisons between replays:
    // zero our 8 accumulators every call.
    (void)hipMemsetAsync(ws, 0, NY * sizeof(float), stream);

    const int block = 256;
    const int grid  = 2048;               // 8 blocks/CU, grid-stride covers the rest
    rmse_partial_kernel<<<grid, block, 0, stream>>>(outp, tgtp, ws);
    rmse_final_kernel<<<1, 64, 0, stream>>>(ws, out);
}

// Round 4
// 235.171 us; speedup vs baseline: 1.4401x; 1.4401x over previous
//
#include <hip/hip_runtime.h>
#include <hip/hip_bf16.h>
#include <math.h>

#define NT 1200
#define NB 16384
#define NY 8
#define NGROUPS (NT * NB)                 // 19,660,800 channel-groups
#define NQ      (NT * NB * NY / 4)        // 39,321,600 float4 elements
#define Q_PER_T (NB * NY / 4)             // 32768 float4 per timestep -> t = q >> 15
#define W_LOW  0.2f
#define W_HIGH 1.75f

typedef float f32x4 __attribute__((ext_vector_type(4)));

// Stage 1: one float4 per thread per iteration — perfectly coalesced
// (lane i reads base+16i; 1 KiB per wave per instruction, no line overlap).
// Thread parity (tid&1) decides whether its float4 is channels 0-3 or 4-7.
__global__ __launch_bounds__(256) void rmse_partial_kernel(
    const float* __restrict__ outp, const float* __restrict__ tgtp,
    float* __restrict__ ws)
{
    const int stride = gridDim.x * blockDim.x;      // 524288, even
    const f32x4* __restrict__ o4 = reinterpret_cast<const f32x4*>(outp);
    const f32x4* __restrict__ t4 = reinterpret_cast<const f32x4*>(tgtp);

    f32x4 acc = {0.0f, 0.0f, 0.0f, 0.0f};

    for (int q = blockIdx.x * blockDim.x + threadIdx.x; q < NQ; q += stride) {
        const int t   = q >> 15;                    // q / (NB*NY/4)
        const int mon = t % 12;
        const float w  = (mon >= 6 && mon <= 9) ? W_HIGH : W_LOW;
        const float w2 = w * w;

        f32x4 a = o4[q];
        f32x4 b = t4[q];
        f32x4 d = a - b;
        acc += (w2 * d) * d;
    }

    // Parity of this thread's channels is fixed: even tid -> ch0-3, odd -> ch4-7.
    // XOR-butterfly with even masks reduces within each parity class.
#pragma unroll
    for (int mask = 2; mask <= 32; mask <<= 1) {
        acc.x += __shfl_xor(acc.x, mask, 64);
        acc.y += __shfl_xor(acc.y, mask, 64);
        acc.z += __shfl_xor(acc.z, mask, 64);
        acc.w += __shfl_xor(acc.w, mask, 64);
    }
    // Now lane 0 holds ch0-3 sum of its wave, lane 1 holds ch4-7 sum.

    __shared__ float sh[4][NY];                     // 4 waves per 256-thread block
    const int wave = threadIdx.x >> 6;
    const int lane = threadIdx.x & 63;
    if (lane < 2) {
        sh[wave][lane * 4 + 0] = acc.x;
        sh[wave][lane * 4 + 1] = acc.y;
        sh[wave][lane * 4 + 2] = acc.z;
        sh[wave][lane * 4 + 3] = acc.w;
    }
    __syncthreads();

    if (threadIdx.x < NY) {
        const int c = threadIdx.x;
        float s = sh[0][c] + sh[1][c] + sh[2][c] + sh[3][c];
        atomicAdd(&ws[c], s);                       // device-scope by default
    }
}

// Stage 2: finalize — sum over channels of sqrt(mean).
__global__ void rmse_final_kernel(const float* __restrict__ ws, float* __restrict__ out)
{
    if (threadIdx.x == 0 && blockIdx.x == 0) {
        const float inv_n = 1.0f / (float)NGROUPS;  // mean over NT*NB per channel
        float s = 0.0f;
#pragma unroll
        for (int c = 0; c < NY; ++c)
            s += sqrtf(ws[c] * inv_n);
        out[0] = s;
    }
}

extern "C" void kernel_launch(void* const* d_in, const int* in_sizes, int n_in,
                              void* d_out, int out_size, void* d_ws, size_t ws_size,
                              hipStream_t stream) {
    const float* outp = (const float*)d_in[0];
    const float* tgtp = (const float*)d_in[1];
    float* ws  = (float*)d_ws;
    float* out = (float*)d_out;

    // Harness poisons d_ws once and never re-poisons between replays:
    // zero our 8 accumulators every call.
    (void)hipMemsetAsync(ws, 0, NY * sizeof(float), stream);

    const int block = 256;
    const int grid  = 2048;                         // 8 blocks/CU; NQ = 75 * grid*block exactly
    rmse_partial_kernel<<<grid, block, 0, stream>>>(outp, tgtp, ws);
    rmse_final_kernel<<<1, 64, 0, stream>>>(ws, out);
}